// Round 1
// baseline (1182.420 us; speedup 1.0000x reference)
//
#include <hip/hip_runtime.h>
#include <hip/hip_bf16.h>
#include <type_traits>

typedef unsigned short u16;
typedef unsigned int u32;
typedef unsigned long long u64;
typedef u16 u16x8 __attribute__((ext_vector_type(8)));
typedef __bf16 bf16x8 __attribute__((ext_vector_type(8)));
typedef float f32x4 __attribute__((ext_vector_type(4)));

#define D_FF   11008
#define NROWS  2048
#define NDIM   4096
#define KTOK   2201
#define KCORE  2201
#define NSPLIT 2201
#define TARGET 4403
#define NREM   (D_FF - NSPLIT)   // 8807

// f32 -> bf16 round-to-nearest-even (inputs are finite; no NaN path needed)
__device__ __forceinline__ u16 f2bf(float f) {
  u32 u = __float_as_uint(f);
  u32 r = u + 0x7fffu + ((u >> 16) & 1u);
  return (u16)(r >> 16);
}

// async global->LDS, 16B per lane. LDS dest is wave-uniform base + lane*16
// (m104/m108): pass the chunk base (lane-invariant expression); global src is
// per-lane.
__device__ __forceinline__ void gload_lds16(const u16* g, u16* l) {
  __builtin_amdgcn_global_load_lds((const __attribute__((address_space(1))) void*)g,
                                   (__attribute__((address_space(3))) void*)l,
                                   16, 0, 0);
}

// ---------------------------------------------------------------------------
// Kernel A: per-row exact top-KTOK membership -> counts[f] increments.
// f32 values mapped to 32-bit monotonic keys; 4-pass byte-radix histogram
// finds the rank-KTOK threshold key T exactly. Elements > T selected; first
// `need` elements == T (ascending index) replicate lax.top_k tie-break.
// Fused: also emits the bf16 copy of x (row-major) when xb != nullptr, so the
// separate 135MB cvt pass over x is not needed.
// ---------------------------------------------------------------------------
__global__ __launch_bounds__(256) void row_topk_counts(const float* __restrict__ x,
                                                       int* __restrict__ counts,
                                                       u16* __restrict__ xb) {
  const int row = blockIdx.x;
  const int tid = threadIdx.x;
  __shared__ u32 keys[D_FF];        // 44 KB
  __shared__ int hist[256];
  __shared__ u32 s_pref;
  __shared__ int s_r;

  const float* xr = x + (size_t)row * D_FF;
  u16* xbr = xb ? (xb + (size_t)row * D_FF) : (u16*)0;
  for (int f = tid; f < D_FF; f += 256) {
    float v = xr[f];
    u32 b = __float_as_uint(v);
    keys[f] = (b & 0x80000000u) ? ~b : (b | 0x80000000u);
    if (xbr) xbr[f] = f2bf(v);
  }
  if (tid == 0) { s_pref = 0; s_r = KTOK; }
  __syncthreads();

  #pragma unroll
  for (int shift = 24; shift >= 0; shift -= 8) {
    hist[tid] = 0;
    __syncthreads();
    const u64 pref = (u64)s_pref;
    for (int f = tid; f < D_FF; f += 256) {
      u32 k = keys[f];
      if (((u64)k >> (shift + 8)) == pref)   // u64 shift: safe at shift==24
        atomicAdd(&hist[(k >> shift) & 0xffu], 1);
    }
    __syncthreads();
    if (tid == 0) {
      int r = s_r, cum = 0;
      for (int b = 255; b >= 0; --b) {
        int c = hist[b];
        if (cum + c >= r) { s_pref = (s_pref << 8) | (u32)b; s_r = r - cum; break; }
        cum += c;
      }
    }
    __syncthreads();
  }

  const u32 T = s_pref;
  const int need = s_r;          // how many ==T elements to take (lowest idx)
  for (int f = tid; f < D_FF; f += 256)
    if (keys[f] > T) atomicAdd(&counts[f], 1);
  if (tid < 64) {
    int taken = 0;
    for (int base = 0; base < D_FF; base += 64) {
      int f = base + tid;
      bool eq = (keys[f] == T);
      u64 m = __ballot(eq);
      int before = __popcll(m & ((1ull << tid) - 1ull));
      if (eq && (taken + before) < need) atomicAdd(&counts[f], 1);
      taken += __popcll(m);
      if (taken >= need) break;
    }
  }
}

// ---------------------------------------------------------------------------
// Kernel B (single block): core = top-KCORE of counts (tie-break low index),
// union with model_neurons[:NSPLIT], then coef[f] = x_dec[pos of f in idx_all].
// Writes both f32 and bf16 coef vectors.
// ---------------------------------------------------------------------------
__global__ __launch_bounds__(256) void build_coef(const int* __restrict__ counts,
                                                  const int* __restrict__ mn,
                                                  const float* __restrict__ xdec,
                                                  float* __restrict__ coef_f,
                                                  u16* __restrict__ coef_h) {
  const int tid = threadIdx.x;
  __shared__ int hist[2049];
  __shared__ unsigned char uni[D_FF];
  __shared__ int cs[256];
  __shared__ int s_Tc, s_need, s_U;

  for (int i = tid; i < 2049; i += 256) hist[i] = 0;
  __syncthreads();
  for (int f = tid; f < D_FF; f += 256) atomicAdd(&hist[counts[f]], 1);
  __syncthreads();
  if (tid == 0) {
    int cum = 0, Tc = 0;
    for (int b = 2048; b >= 0; --b) {
      int c = hist[b];
      if (cum + c >= KCORE) { Tc = b; break; }
      cum += c;
    }
    s_Tc = Tc;
    s_need = KCORE - cum;
  }
  __syncthreads();
  const int Tc = s_Tc;
  const int need = s_need;
  for (int f = tid; f < D_FF; f += 256) uni[f] = (counts[f] > Tc) ? 1 : 0;
  __syncthreads();
  if (tid < 64) {
    int taken = 0;
    for (int base = 0; base < D_FF; base += 64) {
      int f = base + tid;
      bool eq = (counts[f] == Tc);
      u64 m = __ballot(eq);
      int before = __popcll(m & ((1ull << tid) - 1ull));
      if (eq && (taken + before) < need) uni[f] = 1;
      taken += __popcll(m);
      if (taken >= need) break;
    }
  }
  __syncthreads();
  for (int j = tid; j < NSPLIT; j += 256) uni[mn[j]] = 1;
  __syncthreads();

  // union members (ascending f) occupy positions 0..U-1 of idx_all
  {
    int s = 0;
    const int base = tid * 43;           // 256*43 == 11008
    for (int i = 0; i < 43; ++i) s += uni[base + i];
    cs[tid] = s;
  }
  __syncthreads();
  if (tid == 0) {
    int run = 0;
    for (int t = 0; t < 256; ++t) { int v = cs[t]; cs[t] = run; run += v; }
    s_U = run;
  }
  __syncthreads();
  {
    int k = cs[tid];
    const int base = tid * 43;
    for (int i = 0; i < 43; ++i) {
      int f = base + i;
      if (uni[f]) {                      // U <= 4402 < TARGET always
        float v = xdec[k];
        coef_f[f] = v;
        coef_h[f] = f2bf(v);
        ++k;
      }
    }
  }
  __syncthreads();
  const int U = s_U;

  // remaining TARGET-U slots from rem (model_neurons order, non-union only)
  int s2 = 0;
  const int j0 = tid * 35;               // 256*35 >= 8807
  const int j1 = (j0 + 35 < NREM) ? (j0 + 35) : NREM;
  for (int j = j0; j < j1; ++j) s2 += uni[mn[NSPLIT + j]] ? 0 : 1;
  __syncthreads();
  cs[tid] = s2;
  __syncthreads();
  if (tid == 0) {
    int run = 0;
    for (int t = 0; t < 256; ++t) { int v = cs[t]; cs[t] = run; run += v; }
  }
  __syncthreads();
  {
    int k = U + cs[tid];
    for (int j = j0; j < j1; ++j) {
      int f = mn[NSPLIT + j];
      if (!uni[f]) {
        if (k < TARGET) {
          float v = xdec[k];
          coef_f[f] = v;
          coef_h[f] = f2bf(v);
        }
        ++k;
      }
    }
  }
}

// ---------------------------------------------------------------------------
// f32 -> bf16 bulk convert (8 elements / thread, 32B read / 16B write) — W only
// ---------------------------------------------------------------------------
__global__ __launch_bounds__(256) void cvt_bf16(const float* __restrict__ in,
                                                u16* __restrict__ outp, int n8) {
  int i = blockIdx.x * 256 + threadIdx.x;
  if (i >= n8) return;
  const float4* p = (const float4*)in + 2 * (size_t)i;
  float4 a = p[0], b = p[1];
  u16x8 h;
  h[0] = f2bf(a.x); h[1] = f2bf(a.y); h[2] = f2bf(a.z); h[3] = f2bf(a.w);
  h[4] = f2bf(b.x); h[5] = f2bf(b.y); h[6] = f2bf(b.z); h[7] = f2bf(b.w);
  *((u16x8*)outp + i) = h;
}

__device__ __forceinline__ u16x8 pack8(float4 a, float4 b) {
  u16x8 h;
  h[0] = f2bf(a.x); h[1] = f2bf(a.y); h[2] = f2bf(a.z); h[3] = f2bf(a.w);
  h[4] = f2bf(b.x); h[5] = f2bf(b.y); h[6] = f2bf(b.z); h[7] = f2bf(b.w);
  return h;
}

// ---------------------------------------------------------------------------
// Fast GEMM (bf16 inputs): C(2049x4096) = A(2049x11008) * W(4096x11008)^T.
// m97 structure: 128x128 tile, BK=32, 4 waves x (64x64 via 4x4 mfma 16x16x32),
// staging via global_load_lds width=16 (direct HBM->LDS, no VGPR round-trip),
// linear LDS [128][32] u16 (global_load_lds requires linear lane order).
// Per K-step each thread issues 2 A-chunk + 2 B-chunk loads:
//   chunk c (of 8) = 1024 B = 16 rows; lane l covers row c*16+(l>>2),
//   k-halves (l&3)*8 — matches HW's base+lane*16 fan-out exactly.
// ---------------------------------------------------------------------------
__global__ __launch_bounds__(256) void gemm_lds(const u16* __restrict__ xb,
                                                const u16* __restrict__ wb,
                                                const u16* __restrict__ coef,
                                                float* __restrict__ out) {
  __shared__ alignas(16) u16 As[128 * 32];   // 8 KB
  __shared__ alignas(16) u16 Bs[128 * 32];   // 8 KB
  const int tid  = threadIdx.x;
  const int lane = tid & 63;
  const int w    = tid >> 6;
  const int bn   = blockIdx.x;   // 0..31
  const int bm   = blockIdx.y;   // 0..16
  const int wm   = w & 1;
  const int wn   = w >> 1;

  const u16* gA[2];
  const u16* gB[2];
  u16* lA[2];
  u16* lB[2];
  #pragma unroll
  for (int i = 0; i < 2; ++i) {
    const int c  = w * 2 + i;            // chunk 0..7 (lane-invariant)
    const int rA = c * 16 + (lane >> 2); // tile row this lane sources
    const int kk = (lane & 3) * 8;       // k-offset (u16 elems) this lane sources
    int R = bm * 128 + rA;
    if (R > NROWS) R = NROWS;            // pad rows re-load coef row; never stored
    gA[i] = ((R == NROWS) ? coef : (xb + (size_t)R * D_FF)) + kk;
    gB[i] = wb + (size_t)(bn * 128 + rA) * D_FF + kk;
    lA[i] = &As[c * 512];                // chunk base: wave-uniform
    lB[i] = &Bs[c * 512];
  }

  f32x4 acc[4][4] = {};
  const int r16 = lane & 15;
  const int kg  = (lane >> 4) * 8;

  for (int k0 = 0; k0 < D_FF; k0 += 32) {
    #pragma unroll
    for (int i = 0; i < 2; ++i) {
      gload_lds16(gA[i] + k0, lA[i]);
      gload_lds16(gB[i] + k0, lB[i]);
    }
    __syncthreads();               // drains vmcnt: tile resident in LDS
    bf16x8 af[4], bf[4];
    #pragma unroll
    for (int mi = 0; mi < 4; ++mi)
      af[mi] = *(const bf16x8*)&As[(wm * 64 + mi * 16 + r16) * 32 + kg];
    #pragma unroll
    for (int ni = 0; ni < 4; ++ni)
      bf[ni] = *(const bf16x8*)&Bs[(wn * 64 + ni * 16 + r16) * 32 + kg];
    #pragma unroll
    for (int mi = 0; mi < 4; ++mi)
      #pragma unroll
      for (int ni = 0; ni < 4; ++ni)
        acc[mi][ni] = __builtin_amdgcn_mfma_f32_16x16x32_bf16(af[mi], bf[ni],
                                                              acc[mi][ni], 0, 0, 0);
    __syncthreads();               // all ds_reads done before next overwrite
  }

  // C/D layout (m89-verified): col = lane&15, row = (lane>>4)*4 + reg
  #pragma unroll
  for (int mi = 0; mi < 4; ++mi) {
    const int rbase = bm * 128 + wm * 64 + mi * 16 + (lane >> 4) * 4;
    #pragma unroll
    for (int ni = 0; ni < 4; ++ni) {
      const int c = bn * 128 + wn * 64 + ni * 16 + r16;
      #pragma unroll
      for (int q = 0; q < 4; ++q) {
        const int r = rbase + q;
        if (r <= NROWS)
          out[(size_t)r * NDIM + c] = acc[mi][ni][q];
      }
    }
  }
}

// ---------------------------------------------------------------------------
// Fallback GEMM (small workspace): f32 inputs, convert during register staging.
// ---------------------------------------------------------------------------
__global__ __launch_bounds__(256) void gemm_bt_cvt(const float* __restrict__ xv,
                                                   const float* __restrict__ wv,
                                                   const float* __restrict__ cv,
                                                   float* __restrict__ out) {
  __shared__ alignas(16) u16 As[128 * 32];
  __shared__ alignas(16) u16 Bs[128 * 32];
  const int tid  = threadIdx.x;
  const int lane = tid & 63;
  const int bn   = blockIdx.x;
  const int bm   = blockIdx.y;
  const int wid  = tid >> 6;
  const int wm   = wid & 1;
  const int wn   = wid >> 1;

  const int r0 = tid >> 2;
  const int kk = (tid & 3) * 8;

  const float* ag[2];
  const float* bg[2];
  u16* al[2];
  u16* bl[2];
  #pragma unroll
  for (int p = 0; p < 2; ++p) {
    const int rl = p * 64 + r0;
    int R = bm * 128 + rl;
    if (R > NROWS) R = NROWS;
    ag[p] = ((R == NROWS) ? cv : (xv + (size_t)R * D_FF)) + kk;
    bg[p] = wv + (size_t)(bn * 128 + rl) * D_FF + kk;
    al[p] = &As[rl * 32 + kk];
    bl[p] = &Bs[rl * 32 + kk];
  }

  f32x4 acc[4][4] = {};
  const int r16 = lane & 15;
  const int kg  = (lane >> 4) * 8;

  for (int k0 = 0; k0 < D_FF; k0 += 32) {
    u16x8 sa[2], sb[2];
    #pragma unroll
    for (int p = 0; p < 2; ++p) {
      const float* pa = ag[p] + k0;
      const float* pb = bg[p] + k0;
      sa[p] = pack8(*(const float4*)pa, *(const float4*)(pa + 4));
      sb[p] = pack8(*(const float4*)pb, *(const float4*)(pb + 4));
    }
    __syncthreads();
    #pragma unroll
    for (int p = 0; p < 2; ++p) {
      *(u16x8*)al[p] = sa[p];
      *(u16x8*)bl[p] = sb[p];
    }
    __syncthreads();
    bf16x8 af[4], bf[4];
    #pragma unroll
    for (int mi = 0; mi < 4; ++mi)
      af[mi] = *(const bf16x8*)&As[(wm * 64 + mi * 16 + r16) * 32 + kg];
    #pragma unroll
    for (int ni = 0; ni < 4; ++ni)
      bf[ni] = *(const bf16x8*)&Bs[(wn * 64 + ni * 16 + r16) * 32 + kg];
    #pragma unroll
    for (int mi = 0; mi < 4; ++mi)
      #pragma unroll
      for (int ni = 0; ni < 4; ++ni)
        acc[mi][ni] = __builtin_amdgcn_mfma_f32_16x16x32_bf16(af[mi], bf[ni],
                                                              acc[mi][ni], 0, 0, 0);
  }

  #pragma unroll
  for (int mi = 0; mi < 4; ++mi) {
    const int rbase = bm * 128 + wm * 64 + mi * 16 + (lane >> 4) * 4;
    #pragma unroll
    for (int ni = 0; ni < 4; ++ni) {
      const int c = bn * 128 + wn * 64 + ni * 16 + r16;
      #pragma unroll
      for (int q = 0; q < 4; ++q) {
        const int r = rbase + q;
        if (r <= NROWS)
          out[(size_t)r * NDIM + c] = acc[mi][ni][q];
      }
    }
  }
}

extern "C" void kernel_launch(void* const* d_in, const int* in_sizes, int n_in,
                              void* d_out, int out_size, void* d_ws, size_t ws_size,
                              hipStream_t stream) {
  (void)in_sizes; (void)n_in; (void)out_size;
  const float* x    = (const float*)d_in[0];   // f32 (1,2048,11008)
  const float* w    = (const float*)d_in[1];   // f32 (4096,11008)
  const float* xdec = (const float*)d_in[2];   // f32 (4403)
  const int*   mn   = (const int*)d_in[3];     // int32 (11008)
  float* out = (float*)d_out;                  // f32 (2049*4096)

  char* ws = (char*)d_ws;
  int*   counts = (int*)ws;                        // 44032 B
  float* coef_f = (float*)(ws + 44032);            // 44032 B
  u16*   coef_h = (u16*)(ws + 88064);              // 22016 B
  u16*   xb     = (u16*)(ws + 110080);             // 45,088,768 B
  u16*   wb     = (u16*)(ws + 110080 + 45088768ull); // 90,177,536 B
  const size_t need_fast = 110080ull + 45088768ull + 90177536ull;
  const bool fast = (ws_size >= need_fast);

  hipMemsetAsync(d_ws, 0, 110080, stream);
  row_topk_counts<<<NROWS, 256, 0, stream>>>(x, counts, fast ? xb : (u16*)0);
  build_coef<<<1, 256, 0, stream>>>(counts, mn, xdec, coef_f, coef_h);

  if (fast) {
    cvt_bf16<<<(NDIM * D_FF / 8 + 255) / 256, 256, 0, stream>>>(w, wb, NDIM * D_FF / 8);
    gemm_lds<<<dim3(32, 17), 256, 0, stream>>>(xb, wb, coef_h, out);
  } else {
    gemm_bt_cvt<<<dim3(32, 17), 256, 0, stream>>>(x, w, coef_f, out);
  }
}

// Round 2
// 1073.671 us; speedup vs baseline: 1.1013x; 1.1013x over previous
//
#include <hip/hip_runtime.h>
#include <hip/hip_bf16.h>
#include <type_traits>

typedef unsigned short u16;
typedef unsigned int u32;
typedef unsigned long long u64;
typedef u16 u16x4 __attribute__((ext_vector_type(4)));
typedef u16 u16x8 __attribute__((ext_vector_type(8)));
typedef u32 u32x4 __attribute__((ext_vector_type(4)));
typedef __bf16 bf16x8 __attribute__((ext_vector_type(8)));
typedef float f32x4 __attribute__((ext_vector_type(4)));

#define D_FF   11008
#define NROWS  2048
#define NDIM   4096
#define KTOK   2201
#define KCORE  2201
#define NSPLIT 2201
#define TARGET 4403
#define NREM   (D_FF - NSPLIT)   // 8807
#define NWORD  172               // 172*64 == 11008 mask words per row

// f32 -> bf16 round-to-nearest-even (inputs are finite; no NaN path needed)
__device__ __forceinline__ u16 f2bf(float f) {
  u32 u = __float_as_uint(f);
  u32 r = u + 0x7fffu + ((u >> 16) & 1u);
  return (u16)(r >> 16);
}

// async global->LDS, 16B per lane. LDS dest is wave-uniform base + lane*16
// (m104/m108): pass the chunk base (lane-invariant); global src is per-lane.
__device__ __forceinline__ void gload_lds16(const u16* g, u16* l) {
  __builtin_amdgcn_global_load_lds((const __attribute__((address_space(1))) void*)g,
                                   (__attribute__((address_space(3))) void*)l,
                                   16, 0, 0);
}

// ---------------------------------------------------------------------------
// Kernel A: per-row exact top-KTOK selection -> per-row 64-bit ballot masks
// (NO global atomics: the old 4.5M device-scope atomicAdds bounced ~700 cache
// lines across 8 non-coherent XCD L2s). Radix threshold logic unchanged.
// Fused: emits bf16 copy of x when xb != nullptr.
// ---------------------------------------------------------------------------
__global__ __launch_bounds__(256) void row_topk_mask(const float* __restrict__ x,
                                                     u64* __restrict__ rowmask,
                                                     u16* __restrict__ xb) {
  const int row = blockIdx.x;
  const int tid = threadIdx.x;
  __shared__ u32 keys[D_FF];        // 44 KB
  __shared__ u64 tiemask[NWORD];    // 1376 B
  __shared__ int hist[256];
  __shared__ u32 s_pref;
  __shared__ int s_r;

  const float* xr = x + (size_t)row * D_FF;
  u16* xbr = xb ? (xb + (size_t)row * D_FF) : (u16*)0;
  for (int i = tid; i < D_FF / 4; i += 256) {       // 2752 float4s
    float4 v = ((const float4*)xr)[i];
    u32x4 kv;
    u32 b0 = __float_as_uint(v.x), b1 = __float_as_uint(v.y);
    u32 b2 = __float_as_uint(v.z), b3 = __float_as_uint(v.w);
    kv[0] = (b0 & 0x80000000u) ? ~b0 : (b0 | 0x80000000u);
    kv[1] = (b1 & 0x80000000u) ? ~b1 : (b1 | 0x80000000u);
    kv[2] = (b2 & 0x80000000u) ? ~b2 : (b2 | 0x80000000u);
    kv[3] = (b3 & 0x80000000u) ? ~b3 : (b3 | 0x80000000u);
    ((u32x4*)keys)[i] = kv;
    if (xbr) {
      u16x4 hv;
      hv[0] = f2bf(v.x); hv[1] = f2bf(v.y); hv[2] = f2bf(v.z); hv[3] = f2bf(v.w);
      ((u16x4*)xbr)[i] = hv;
    }
  }
  for (int i = tid; i < NWORD; i += 256) tiemask[i] = 0;
  if (tid == 0) { s_pref = 0; s_r = KTOK; }
  __syncthreads();

  #pragma unroll
  for (int shift = 24; shift >= 0; shift -= 8) {
    hist[tid] = 0;
    __syncthreads();
    const u64 pref = (u64)s_pref;
    for (int f = tid; f < D_FF; f += 256) {
      u32 k = keys[f];
      if (((u64)k >> (shift + 8)) == pref)   // u64 shift: safe at shift==24
        atomicAdd(&hist[(k >> shift) & 0xffu], 1);
    }
    __syncthreads();
    if (tid == 0) {
      int r = s_r, cum = 0;
      for (int b = 255; b >= 0; --b) {
        int c = hist[b];
        if (cum + c >= r) { s_pref = (s_pref << 8) | (u32)b; s_r = r - cum; break; }
        cum += c;
      }
    }
    __syncthreads();
  }

  const u32 T = s_pref;
  const int need = s_r;          // how many ==T elements to take (lowest idx)
  if (tid < 64) {                // wave 0: tie-break, lowest indices first
    int taken = 0;
    for (int base = 0; base < D_FF; base += 64) {
      int f = base + tid;
      bool eq = (keys[f] == T);
      u64 m = __ballot(eq);
      int before = __popcll(m & ((1ull << tid) - 1ull));
      u64 tw = __ballot(eq && (taken + before) < need);
      if (tid == 0) tiemask[base >> 6] = tw;
      taken += __popcll(m);
      if (taken >= need) break;
    }
  }
  __syncthreads();
  u64* mr = rowmask + (size_t)row * NWORD;
  for (int f = tid; f < D_FF; f += 256) {  // wave w covers a contiguous 64-block
    u64 m = __ballot(keys[f] > T);
    if ((tid & 63) == 0) mr[f >> 6] = m | tiemask[f >> 6];
  }
}

// ---------------------------------------------------------------------------
// Kernel A2: counts[f] = sum over 2048 rows of mask bit f. 172 blocks.
// ---------------------------------------------------------------------------
__global__ __launch_bounds__(256) void count_bits(const u64* __restrict__ rowmask,
                                                  int* __restrict__ counts) {
  __shared__ u64 w[NROWS];          // 16 KB
  __shared__ int partial[256];
  const int g = blockIdx.x;         // word index 0..171
  const int tid = threadIdx.x;
  for (int r = tid; r < NROWS; r += 256) w[r] = rowmask[(size_t)r * NWORD + g];
  __syncthreads();
  const int b = tid & 63;
  const int c0 = (tid >> 6) * 512;
  int s = 0;
  for (int r = c0; r < c0 + 512; ++r) s += (int)((w[r] >> b) & 1);  // LDS broadcast
  partial[tid] = s;
  __syncthreads();
  if (tid < 64)
    counts[g * 64 + b] = partial[b] + partial[64 + b] + partial[128 + b] + partial[192 + b];
}

// ---------------------------------------------------------------------------
// Kernel B (single block): core = top-KCORE of counts (tie-break low index),
// union with model_neurons[:NSPLIT], then coef[f] = x_dec[pos of f in idx_all].
// ---------------------------------------------------------------------------
__global__ __launch_bounds__(256) void build_coef(const int* __restrict__ counts,
                                                  const int* __restrict__ mn,
                                                  const float* __restrict__ xdec,
                                                  float* __restrict__ coef_f,
                                                  u16* __restrict__ coef_h) {
  const int tid = threadIdx.x;
  __shared__ int hist[2049];
  __shared__ unsigned char uni[D_FF];
  __shared__ int cs[256];
  __shared__ int s_Tc, s_need, s_U;

  for (int i = tid; i < 2049; i += 256) hist[i] = 0;
  __syncthreads();
  for (int f = tid; f < D_FF; f += 256) atomicAdd(&hist[counts[f]], 1);
  __syncthreads();
  if (tid == 0) {
    int cum = 0, Tc = 0;
    for (int b = 2048; b >= 0; --b) {
      int c = hist[b];
      if (cum + c >= KCORE) { Tc = b; break; }
      cum += c;
    }
    s_Tc = Tc;
    s_need = KCORE - cum;
  }
  __syncthreads();
  const int Tc = s_Tc;
  const int need = s_need;
  for (int f = tid; f < D_FF; f += 256) uni[f] = (counts[f] > Tc) ? 1 : 0;
  __syncthreads();
  if (tid < 64) {
    int taken = 0;
    for (int base = 0; base < D_FF; base += 64) {
      int f = base + tid;
      bool eq = (counts[f] == Tc);
      u64 m = __ballot(eq);
      int before = __popcll(m & ((1ull << tid) - 1ull));
      if (eq && (taken + before) < need) uni[f] = 1;
      taken += __popcll(m);
      if (taken >= need) break;
    }
  }
  __syncthreads();
  for (int j = tid; j < NSPLIT; j += 256) uni[mn[j]] = 1;
  __syncthreads();

  // union members (ascending f) occupy positions 0..U-1 of idx_all
  {
    int s = 0;
    const int base = tid * 43;           // 256*43 == 11008
    for (int i = 0; i < 43; ++i) s += uni[base + i];
    cs[tid] = s;
  }
  __syncthreads();
  if (tid == 0) {
    int run = 0;
    for (int t = 0; t < 256; ++t) { int v = cs[t]; cs[t] = run; run += v; }
    s_U = run;
  }
  __syncthreads();
  {
    int k = cs[tid];
    const int base = tid * 43;
    for (int i = 0; i < 43; ++i) {
      int f = base + i;
      if (uni[f]) {                      // U <= 4402 < TARGET always
        float v = xdec[k];
        coef_f[f] = v;
        coef_h[f] = f2bf(v);
        ++k;
      }
    }
  }
  __syncthreads();
  const int U = s_U;

  // remaining TARGET-U slots from rem (model_neurons order, non-union only)
  int s2 = 0;
  const int j0 = tid * 35;               // 256*35 >= 8807
  const int j1 = (j0 + 35 < NREM) ? (j0 + 35) : NREM;
  for (int j = j0; j < j1; ++j) s2 += uni[mn[NSPLIT + j]] ? 0 : 1;
  __syncthreads();
  cs[tid] = s2;
  __syncthreads();
  if (tid == 0) {
    int run = 0;
    for (int t = 0; t < 256; ++t) { int v = cs[t]; cs[t] = run; run += v; }
  }
  __syncthreads();
  {
    int k = U + cs[tid];
    for (int j = j0; j < j1; ++j) {
      int f = mn[NSPLIT + j];
      if (!uni[f]) {
        if (k < TARGET) {
          float v = xdec[k];
          coef_f[f] = v;
          coef_h[f] = f2bf(v);
        }
        ++k;
      }
    }
  }
}

// ---------------------------------------------------------------------------
// f32 -> bf16 bulk convert (8 elements / thread) — W only
// ---------------------------------------------------------------------------
__global__ __launch_bounds__(256) void cvt_bf16(const float* __restrict__ in,
                                                u16* __restrict__ outp, int n8) {
  int i = blockIdx.x * 256 + threadIdx.x;
  if (i >= n8) return;
  const float4* p = (const float4*)in + 2 * (size_t)i;
  float4 a = p[0], b = p[1];
  u16x8 h;
  h[0] = f2bf(a.x); h[1] = f2bf(a.y); h[2] = f2bf(a.z); h[3] = f2bf(a.w);
  h[4] = f2bf(b.x); h[5] = f2bf(b.y); h[6] = f2bf(b.z); h[7] = f2bf(b.w);
  *((u16x8*)outp + i) = h;
}

__device__ __forceinline__ u16x8 pack8(float4 a, float4 b) {
  u16x8 h;
  h[0] = f2bf(a.x); h[1] = f2bf(a.y); h[2] = f2bf(a.z); h[3] = f2bf(a.w);
  h[4] = f2bf(b.x); h[5] = f2bf(b.y); h[6] = f2bf(b.z); h[7] = f2bf(b.w);
  return h;
}

// ---------------------------------------------------------------------------
// Fast GEMM, split-K=2: C(2049x4096) += A(2049x11008) * W(4096x11008)^T.
// m97 structure (global_load_lds w=16, linear LDS) + two fixes this round:
//  * split-K=2 (grid 32x17x2 = 1088 blocks -> ~4.25 blocks/CU; was 2.1,
//    latency-bound at Occupancy 14.7%). Partials combined via HW f32 atomic
//    add into zeroed out (2 adds/addr -> deterministic).
//  * LDS XOR swizzle (T2 / rule #21, both-sides): 16B col-block j of row R
//    stored at j^((R>>1)&3) — applied identically on the per-lane GLOBAL
//    source address (buffers stay row-major) and on the ds_read col. Kills
//    the 8-way quarter-wave conflict (SQ_LDS_BANK_CONFLICT 2.4e7).
// ---------------------------------------------------------------------------
__global__ __launch_bounds__(256) void gemm_lds(const u16* __restrict__ xb,
                                                const u16* __restrict__ wb,
                                                const u16* __restrict__ coef,
                                                float* __restrict__ out) {
  __shared__ alignas(16) u16 As[128 * 32];   // 8 KB
  __shared__ alignas(16) u16 Bs[128 * 32];   // 8 KB
  const int tid  = threadIdx.x;
  const int lane = tid & 63;
  const int w    = tid >> 6;
  const int bn   = blockIdx.x;   // 0..31
  const int bm   = blockIdx.y;   // 0..16
  const int kz   = blockIdx.z;   // 0..1  (split-K)
  const int wm   = w & 1;
  const int wn   = w >> 1;

  const u16* gA[2];
  const u16* gB[2];
  u16* lA[2];
  u16* lB[2];
  #pragma unroll
  for (int i = 0; i < 2; ++i) {
    const int c  = w * 2 + i;            // chunk 0..7 (lane-invariant)
    const int rA = c * 16 + (lane >> 2); // tile row this lane sources
    // swizzled source col-block: j=(lane&3) at LDS holds block j^((row>>1)&3)
    const int kk = (((lane & 3) ^ ((lane >> 3) & 3)) * 8);
    int R = bm * 128 + rA;
    if (R > NROWS) R = NROWS;            // pad rows re-load coef row; never stored
    gA[i] = ((R == NROWS) ? coef : (xb + (size_t)R * D_FF)) + kk;
    gB[i] = wb + (size_t)(bn * 128 + rA) * D_FF + kk;
    lA[i] = &As[c * 512];                // chunk base: wave-uniform
    lB[i] = &Bs[c * 512];
  }

  f32x4 acc[4][4] = {};
  const int r16  = lane & 15;
  const int kswz = (((lane >> 4) ^ ((r16 >> 1) & 3)) * 8);  // swizzled read col

  const int kend = kz * (D_FF / 2) + (D_FF / 2);
  for (int k0 = kz * (D_FF / 2); k0 < kend; k0 += 32) {
    #pragma unroll
    for (int i = 0; i < 2; ++i) {
      gload_lds16(gA[i] + k0, lA[i]);
      gload_lds16(gB[i] + k0, lB[i]);
    }
    __syncthreads();               // drains vmcnt: tile resident in LDS
    bf16x8 af[4], bf[4];
    #pragma unroll
    for (int mi = 0; mi < 4; ++mi)
      af[mi] = *(const bf16x8*)&As[(wm * 64 + mi * 16 + r16) * 32 + kswz];
    #pragma unroll
    for (int ni = 0; ni < 4; ++ni)
      bf[ni] = *(const bf16x8*)&Bs[(wn * 64 + ni * 16 + r16) * 32 + kswz];
    #pragma unroll
    for (int mi = 0; mi < 4; ++mi)
      #pragma unroll
      for (int ni = 0; ni < 4; ++ni)
        acc[mi][ni] = __builtin_amdgcn_mfma_f32_16x16x32_bf16(af[mi], bf[ni],
                                                              acc[mi][ni], 0, 0, 0);
    __syncthreads();               // all ds_reads done before next overwrite
  }

  // C/D layout (m89-verified): col = lane&15, row = (lane>>4)*4 + reg
  #pragma unroll
  for (int mi = 0; mi < 4; ++mi) {
    const int rbase = bm * 128 + wm * 64 + mi * 16 + (lane >> 4) * 4;
    #pragma unroll
    for (int ni = 0; ni < 4; ++ni) {
      const int c = bn * 128 + wn * 64 + ni * 16 + r16;
      #pragma unroll
      for (int q = 0; q < 4; ++q) {
        const int r = rbase + q;
        if (r <= NROWS)
          unsafeAtomicAdd(&out[(size_t)r * NDIM + c], acc[mi][ni][q]);
      }
    }
  }
}

// ---------------------------------------------------------------------------
// Fallback GEMM (small workspace): f32 inputs, convert during register staging.
// ---------------------------------------------------------------------------
__global__ __launch_bounds__(256) void gemm_bt_cvt(const float* __restrict__ xv,
                                                   const float* __restrict__ wv,
                                                   const float* __restrict__ cv,
                                                   float* __restrict__ out) {
  __shared__ alignas(16) u16 As[128 * 32];
  __shared__ alignas(16) u16 Bs[128 * 32];
  const int tid  = threadIdx.x;
  const int lane = tid & 63;
  const int bn   = blockIdx.x;
  const int bm   = blockIdx.y;
  const int wid  = tid >> 6;
  const int wm   = wid & 1;
  const int wn   = wid >> 1;

  const int r0 = tid >> 2;
  const int kk = (tid & 3) * 8;

  const float* ag[2];
  const float* bg[2];
  u16* al[2];
  u16* bl[2];
  #pragma unroll
  for (int p = 0; p < 2; ++p) {
    const int rl = p * 64 + r0;
    int R = bm * 128 + rl;
    if (R > NROWS) R = NROWS;
    ag[p] = ((R == NROWS) ? cv : (xv + (size_t)R * D_FF)) + kk;
    bg[p] = wv + (size_t)(bn * 128 + rl) * D_FF + kk;
    al[p] = &As[rl * 32 + kk];
    bl[p] = &Bs[rl * 32 + kk];
  }

  f32x4 acc[4][4] = {};
  const int r16 = lane & 15;
  const int kg  = (lane >> 4) * 8;

  for (int k0 = 0; k0 < D_FF; k0 += 32) {
    u16x8 sa[2], sb[2];
    #pragma unroll
    for (int p = 0; p < 2; ++p) {
      const float* pa = ag[p] + k0;
      const float* pb = bg[p] + k0;
      sa[p] = pack8(*(const float4*)pa, *(const float4*)(pa + 4));
      sb[p] = pack8(*(const float4*)pb, *(const float4*)(pb + 4));
    }
    __syncthreads();
    #pragma unroll
    for (int p = 0; p < 2; ++p) {
      *(u16x8*)al[p] = sa[p];
      *(u16x8*)bl[p] = sb[p];
    }
    __syncthreads();
    bf16x8 af[4], bf[4];
    #pragma unroll
    for (int mi = 0; mi < 4; ++mi)
      af[mi] = *(const bf16x8*)&As[(wm * 64 + mi * 16 + r16) * 32 + kg];
    #pragma unroll
    for (int ni = 0; ni < 4; ++ni)
      bf[ni] = *(const bf16x8*)&Bs[(wn * 64 + ni * 16 + r16) * 32 + kg];
    #pragma unroll
    for (int mi = 0; mi < 4; ++mi)
      #pragma unroll
      for (int ni = 0; ni < 4; ++ni)
        acc[mi][ni] = __builtin_amdgcn_mfma_f32_16x16x32_bf16(af[mi], bf[ni],
                                                              acc[mi][ni], 0, 0, 0);
  }

  #pragma unroll
  for (int mi = 0; mi < 4; ++mi) {
    const int rbase = bm * 128 + wm * 64 + mi * 16 + (lane >> 4) * 4;
    #pragma unroll
    for (int ni = 0; ni < 4; ++ni) {
      const int c = bn * 128 + wn * 64 + ni * 16 + r16;
      #pragma unroll
      for (int q = 0; q < 4; ++q) {
        const int r = rbase + q;
        if (r <= NROWS)
          out[(size_t)r * NDIM + c] = acc[mi][ni][q];
      }
    }
  }
}

extern "C" void kernel_launch(void* const* d_in, const int* in_sizes, int n_in,
                              void* d_out, int out_size, void* d_ws, size_t ws_size,
                              hipStream_t stream) {
  (void)in_sizes; (void)n_in; (void)out_size;
  const float* x    = (const float*)d_in[0];   // f32 (1,2048,11008)
  const float* w    = (const float*)d_in[1];   // f32 (4096,11008)
  const float* xdec = (const float*)d_in[2];   // f32 (4403)
  const int*   mn   = (const int*)d_in[3];     // int32 (11008)
  float* out = (float*)d_out;                  // f32 (2049*4096)

  char* ws = (char*)d_ws;
  int*   counts = (int*)ws;                        // 44032 B
  float* coef_f = (float*)(ws + 44032);            // 44032 B
  u16*   coef_h = (u16*)(ws + 88064);              // 22016 B
  u16*   xb     = (u16*)(ws + 110080);             // 45,088,768 B
  u16*   wb     = (u16*)(ws + 110080 + 45088768ull); // 90,177,536 B
  const size_t need_fast = 110080ull + 45088768ull + 90177536ull;
  const bool fast = (ws_size >= need_fast);
  // rowmask (2048*172*8 = 2,818,048 B): dead after count_bits. In the fast
  // path alias it into wb (cvt of W runs after count_bits, stream-ordered);
  // in the slow path use the xb region.
  u64* rowmask = (u64*)(fast ? (void*)wb : (void*)xb);

  hipMemsetAsync(d_ws, 0, 110080, stream);         // coef_f/coef_h zeroed
  row_topk_mask<<<NROWS, 256, 0, stream>>>(x, rowmask, fast ? xb : (u16*)0);
  count_bits<<<NWORD, 256, 0, stream>>>(rowmask, counts);
  build_coef<<<1, 256, 0, stream>>>(counts, mn, xdec, coef_f, coef_h);

  if (fast) {
    cvt_bf16<<<(NDIM * D_FF / 8 + 255) / 256, 256, 0, stream>>>(w, wb, NDIM * D_FF / 8);
    hipMemsetAsync(out, 0, (size_t)(NROWS + 1) * NDIM * sizeof(float), stream);
    gemm_lds<<<dim3(32, 17, 2), 256, 0, stream>>>(xb, wb, coef_h, out);
  } else {
    gemm_bt_cvt<<<dim3(32, 17), 256, 0, stream>>>(x, w, coef_f, out);
  }
}

// Round 4
// 832.514 us; speedup vs baseline: 1.4203x; 1.2897x over previous
//
#include <hip/hip_runtime.h>
#include <hip/hip_bf16.h>
#include <type_traits>

typedef unsigned short u16;
typedef unsigned int u32;
typedef unsigned long long u64;
typedef u16 u16x4 __attribute__((ext_vector_type(4)));
typedef u16 u16x8 __attribute__((ext_vector_type(8)));
typedef u32 u32x4 __attribute__((ext_vector_type(4)));
typedef __bf16 bf16x8 __attribute__((ext_vector_type(8)));
typedef float f32x4 __attribute__((ext_vector_type(4)));

#define D_FF   11008
#define NROWS  2048
#define NDIM   4096
#define KTOK   2201
#define KCORE  2201
#define NSPLIT 2201
#define TARGET 4403
#define NREM   (D_FF - NSPLIT)   // 8807
#define NWORD  172               // 172*64 == 11008 mask words per row

// f32 -> bf16 round-to-nearest-even (inputs are finite; no NaN path needed)
__device__ __forceinline__ u16 f2bf(float f) {
  u32 u = __float_as_uint(f);
  u32 r = u + 0x7fffu + ((u >> 16) & 1u);
  return (u16)(r >> 16);
}

// async global->LDS, 16B per lane. LDS dest is wave-uniform base + lane*16
// (m104/m108): pass the chunk base (lane-invariant); global src is per-lane.
__device__ __forceinline__ void gload_lds16(const u16* g, u16* l) {
  __builtin_amdgcn_global_load_lds((const __attribute__((address_space(1))) void*)g,
                                   (__attribute__((address_space(3))) void*)l,
                                   16, 0, 0);
}

// inclusive scan across the 64 lanes of a wave
__device__ __forceinline__ int wave_incl_scan(int v) {
  const int lane = threadIdx.x & 63;
  #pragma unroll
  for (int d = 1; d < 64; d <<= 1) {
    int n = __shfl_up(v, d);
    if (lane >= d) v += n;
  }
  return v;
}

// inclusive scan across 256 threads (4 waves); wsum is __shared__ int[4]
__device__ __forceinline__ int block_incl_scan256(int v, int* wsum) {
  const int tid = threadIdx.x;
  const int lane = tid & 63, w = tid >> 6;
  v = wave_incl_scan(v);
  if (lane == 63) wsum[w] = v;
  __syncthreads();
  int off = 0;
  if (w > 0) off += wsum[0];
  if (w > 1) off += wsum[1];
  if (w > 2) off += wsum[2];
  __syncthreads();            // wsum reusable by next call
  return v + off;
}

// keep the lowest `need-before` set bits of w (word-local tie truncation).
// incl = inclusive prefix popcount through this word, pc = popcount(w).
__device__ __forceinline__ u64 trunc_word(u64 w, int incl, int pc, int need) {
  int before = incl - pc;
  if (before >= need) return 0ull;
  if (incl <= need) return w;
  int k = need - before;          // 0 < k < pc, at most one word per row
  u64 m = w, out = 0ull;
  while (k-- > 0) { u64 b = m & (0ull - m); out |= b; m ^= b; }
  return out;
}

// ---------------------------------------------------------------------------
// Kernel A: per-row exact top-KTOK -> 64-bit ballot masks per row.
// All formerly-serial pieces parallelized:
//  * radix bucket-select: 256-thread shuffle suffix-scan (was tid0 x 256
//    dependent LDS reads x 4 passes ~ 56us/block)
//  * per-wave privatized histograms (4x less LDS-atomic contention)
//  * tie-break: per-wave eq ballots -> wave0 prefix popcount -> truncate the
//    single partial word (was a 172-iter dependent walk)
// ---------------------------------------------------------------------------
__global__ __launch_bounds__(256) void row_topk_mask(const float* __restrict__ x,
                                                     u64* __restrict__ rowmask,
                                                     u16* __restrict__ xb) {
  const int row = blockIdx.x;
  const int tid = threadIdx.x;
  const int lane = tid & 63;
  __shared__ u32 keys[D_FF];        // 44 KB
  __shared__ int hist4[4][256];     // 4 KB, per-wave privatized
  __shared__ u64 tiem[NWORD];       // 1376 B
  __shared__ int wsum[4];
  __shared__ u32 s_pref;
  __shared__ int s_r;

  const float* xr = x + (size_t)row * D_FF;
  u16* xbr = xb ? (xb + (size_t)row * D_FF) : (u16*)0;
  for (int i = tid; i < D_FF / 4; i += 256) {       // 2752 float4s
    float4 v = ((const float4*)xr)[i];
    u32x4 kv;
    u32 b0 = __float_as_uint(v.x), b1 = __float_as_uint(v.y);
    u32 b2 = __float_as_uint(v.z), b3 = __float_as_uint(v.w);
    kv[0] = (b0 & 0x80000000u) ? ~b0 : (b0 | 0x80000000u);
    kv[1] = (b1 & 0x80000000u) ? ~b1 : (b1 | 0x80000000u);
    kv[2] = (b2 & 0x80000000u) ? ~b2 : (b2 | 0x80000000u);
    kv[3] = (b3 & 0x80000000u) ? ~b3 : (b3 | 0x80000000u);
    ((u32x4*)keys)[i] = kv;
    if (xbr) {
      u16x4 hv;
      hv[0] = f2bf(v.x); hv[1] = f2bf(v.y); hv[2] = f2bf(v.z); hv[3] = f2bf(v.w);
      ((u16x4*)xbr)[i] = hv;
    }
  }
  if (tid == 0) { s_pref = 0; s_r = KTOK; }
  __syncthreads();

  #pragma unroll
  for (int shift = 24; shift >= 0; shift -= 8) {
    hist4[0][tid] = 0; hist4[1][tid] = 0; hist4[2][tid] = 0; hist4[3][tid] = 0;
    __syncthreads();                 // also publishes prev pass's s_pref/s_r
    const u64 pref = (u64)s_pref;
    const int r = s_r;
    int* hw = hist4[tid >> 6];
    for (int f = tid; f < D_FF; f += 256) {
      u32 k = keys[f];
      if (((u64)k >> (shift + 8)) == pref)   // u64 shift: safe at shift==24
        atomicAdd(&hw[(k >> shift) & 0xffu], 1);
    }
    __syncthreads();
    // parallel bucket-select: thread tid owns bucket rev = 255-tid.
    // incl = #matching keys in buckets >= rev; crossing bucket is unique.
    const int rev = 255 - tid;
    const int cnt = hist4[0][rev] + hist4[1][rev] + hist4[2][rev] + hist4[3][rev];
    const int incl = block_incl_scan256(cnt, wsum);
    const int before = incl - cnt;
    if (before < r && incl >= r) {   // exactly one thread
      s_pref = (s_pref << 8) | (u32)rev;
      s_r = r - before;
    }
  }
  __syncthreads();
  const u32 T = s_pref;
  const int need = s_r;              // >=1: how many ==T to take, lowest idx

  // eq-ballot words: wave w lane l covers f=256i+64w+l -> word f>>6 aligned
  for (int f = tid; f < D_FF; f += 256) {
    u64 m = __ballot(keys[f] == T);
    if (lane == 0) tiem[f >> 6] = m;
  }
  __syncthreads();
  if (tid < 64) {                    // prefix popcount over 172 words, 3 chunks
    u64 wA = tiem[tid];                       int pA = __popcll(wA);
    u64 wB = tiem[64 + tid];                  int pB = __popcll(wB);
    u64 wC = (tid < 44) ? tiem[128 + tid] : 0; int pC = __popcll(wC);
    int sA = wave_incl_scan(pA); int tA = __shfl(sA, 63);
    int sB = wave_incl_scan(pB) + tA; int tB = __shfl(sB, 63);
    int sC = wave_incl_scan(pC) + tB;
    tiem[tid]      = trunc_word(wA, sA, pA, need);
    tiem[64 + tid] = trunc_word(wB, sB, pB, need);
    if (tid < 44) tiem[128 + tid] = trunc_word(wC, sC, pC, need);
  }
  __syncthreads();
  u64* mr = rowmask + (size_t)row * NWORD;
  for (int f = tid; f < D_FF; f += 256) {
    u64 m = __ballot(keys[f] > T);
    if (lane == 0) mr[f >> 6] = m | tiem[f >> 6];
  }
}

// ---------------------------------------------------------------------------
// Kernel A2: counts[f] = sum over 2048 rows of mask bit f. 172 blocks.
// ---------------------------------------------------------------------------
__global__ __launch_bounds__(256) void count_bits(const u64* __restrict__ rowmask,
                                                  int* __restrict__ counts) {
  __shared__ u64 w[NROWS];          // 16 KB
  __shared__ int partial[256];
  const int g = blockIdx.x;         // word index 0..171
  const int tid = threadIdx.x;
  for (int r = tid; r < NROWS; r += 256) w[r] = rowmask[(size_t)r * NWORD + g];
  __syncthreads();
  const int b = tid & 63;
  const int c0 = (tid >> 6) * 512;
  int s = 0;
  for (int r = c0; r < c0 + 512; ++r) s += (int)((w[r] >> b) & 1);  // LDS broadcast
  partial[tid] = s;
  __syncthreads();
  if (tid < 64)
    counts[g * 64 + b] = partial[b] + partial[64 + b] + partial[128 + b] + partial[192 + b];
}

// ---------------------------------------------------------------------------
// Kernel B (single block): core = top-KCORE of counts (tie-break low index),
// union with model_neurons[:NSPLIT], then coef[f] = x_dec[pos of f in idx_all].
// All serial scans parallelized (the 2049-bucket tid0 walk alone was ~100us).
// ---------------------------------------------------------------------------
__global__ __launch_bounds__(256) void build_coef(const int* __restrict__ counts,
                                                  const int* __restrict__ mn,
                                                  const float* __restrict__ xdec,
                                                  float* __restrict__ coef_f,
                                                  u16* __restrict__ coef_h) {
  const int tid = threadIdx.x;
  const int lane = tid & 63;
  __shared__ int hist[2049];        // 8.2 KB
  __shared__ unsigned char uni[D_FF];
  __shared__ u64 em[NWORD];
  __shared__ int wsum[4];
  __shared__ int s_Tc, s_need, s_U;

  for (int i = tid; i < 2049; i += 256) hist[i] = 0;
  __syncthreads();
  for (int f = tid; f < D_FF; f += 256) atomicAdd(&hist[counts[f]], 1);
  __syncthreads();

  // parallel threshold select over 2049 buckets: thread tid owns the 8-bucket
  // chunk [8*(255-tid), 8*(255-tid)+8); bucket 2048 handled as edge.
  {
    const int b2048 = hist[2048];
    const int crev = 255 - tid;
    const int base = crev * 8;
    int csum = 0;
    #pragma unroll
    for (int i = 0; i < 8; ++i) csum += hist[base + i];
    const int incl = block_incl_scan256(csum, wsum);   // sum of chunks >= crev
    int cum = b2048 + incl - csum;                     // # counts > base+7
    if (tid == 0 && b2048 >= KCORE) { s_Tc = 2048; s_need = KCORE; }
    #pragma unroll
    for (int b = base + 7; b >= base; --b) {
      int h = hist[b];
      if (cum < KCORE && cum + h >= KCORE) { s_Tc = b; s_need = KCORE - cum; }
      cum += h;
    }
  }
  __syncthreads();
  const int Tc = s_Tc;
  const int need = s_need;

  for (int f = tid; f < D_FF; f += 256) {
    int c = counts[f];
    uni[f] = (c > Tc) ? 1 : 0;
    u64 m = __ballot(c == Tc);
    if (lane == 0) em[f >> 6] = m;
  }
  __syncthreads();
  if (tid < 64) {
    u64 wA = em[tid];                        int pA = __popcll(wA);
    u64 wB = em[64 + tid];                   int pB = __popcll(wB);
    u64 wC = (tid < 44) ? em[128 + tid] : 0; int pC = __popcll(wC);
    int sA = wave_incl_scan(pA); int tA = __shfl(sA, 63);
    int sB = wave_incl_scan(pB) + tA; int tB = __shfl(sB, 63);
    int sC = wave_incl_scan(pC) + tB;
    em[tid]      = trunc_word(wA, sA, pA, need);
    em[64 + tid] = trunc_word(wB, sB, pB, need);
    if (tid < 44) em[128 + tid] = trunc_word(wC, sC, pC, need);
  }
  __syncthreads();
  for (int f = tid; f < D_FF; f += 256)
    if ((em[f >> 6] >> (f & 63)) & 1) uni[f] = 1;
  for (int j = tid; j < NSPLIT; j += 256) uni[mn[j]] = 1;   // both only set 1
  __syncthreads();

  // union members (ascending f) occupy positions 0..U-1 of idx_all
  {
    int s = 0;
    const int base = tid * 43;           // 256*43 == 11008
    for (int i = 0; i < 43; ++i) s += uni[base + i];
    const int incl = block_incl_scan256(s, wsum);
    if (tid == 255) s_U = incl;
    int k = incl - s;                    // exclusive prefix
    for (int i = 0; i < 43; ++i) {
      int f = base + i;
      if (uni[f]) {                      // U <= 4402 < TARGET always
        float v = xdec[k];
        coef_f[f] = v;
        coef_h[f] = f2bf(v);
        ++k;
      }
    }
  }
  __syncthreads();
  const int U = s_U;

  // remaining TARGET-U slots from rem (model_neurons order, non-union only)
  {
    int s2 = 0;
    const int j0 = tid * 35;             // 256*35 >= 8807
    const int j1 = (j0 + 35 < NREM) ? (j0 + 35) : NREM;
    for (int j = j0; j < j1; ++j) s2 += uni[mn[NSPLIT + j]] ? 0 : 1;
    const int incl2 = block_incl_scan256(s2, wsum);
    int k = U + incl2 - s2;
    for (int j = j0; j < j1; ++j) {
      int f = mn[NSPLIT + j];
      if (!uni[f]) {
        if (k < TARGET) {
          float v = xdec[k];
          coef_f[f] = v;
          coef_h[f] = f2bf(v);
        }
        ++k;
      }
    }
  }
}

// ---------------------------------------------------------------------------
// f32 -> bf16 bulk convert (8 elements / thread) — W only
// ---------------------------------------------------------------------------
__global__ __launch_bounds__(256) void cvt_bf16(const float* __restrict__ in,
                                                u16* __restrict__ outp, int n8) {
  int i = blockIdx.x * 256 + threadIdx.x;
  if (i >= n8) return;
  const float4* p = (const float4*)in + 2 * (size_t)i;
  float4 a = p[0], b = p[1];
  u16x8 h;
  h[0] = f2bf(a.x); h[1] = f2bf(a.y); h[2] = f2bf(a.z); h[3] = f2bf(a.w);
  h[4] = f2bf(b.x); h[5] = f2bf(b.y); h[6] = f2bf(b.z); h[7] = f2bf(b.w);
  *((u16x8*)outp + i) = h;
}

__device__ __forceinline__ u16x8 pack8(float4 a, float4 b) {
  u16x8 h;
  h[0] = f2bf(a.x); h[1] = f2bf(a.y); h[2] = f2bf(a.z); h[3] = f2bf(a.w);
  h[4] = f2bf(b.x); h[5] = f2bf(b.y); h[6] = f2bf(b.z); h[7] = f2bf(b.w);
  return h;
}

// ---------------------------------------------------------------------------
// Fast GEMM, split-K=4: C(2049x4096) += A(2049x11008) * W(4096x11008)^T.
// m97 structure (global_load_lds w=16), both-sides XOR swizzle (conflicts=0
// verified R2), split-K raised 2->4: grid 2176 blocks (~8.5/CU) to lift the
// 26% occupancy latency limit. Partials combine via HW f32 atomics (4/addr).
// ---------------------------------------------------------------------------
__global__ __launch_bounds__(256) void gemm_lds(const u16* __restrict__ xb,
                                                const u16* __restrict__ wb,
                                                const u16* __restrict__ coef,
                                                float* __restrict__ out) {
  __shared__ alignas(16) u16 As[128 * 32];   // 8 KB
  __shared__ alignas(16) u16 Bs[128 * 32];   // 8 KB
  const int tid  = threadIdx.x;
  const int lane = tid & 63;
  const int w    = tid >> 6;
  const int bn   = blockIdx.x;   // 0..31
  const int bm   = blockIdx.y;   // 0..16
  const int kz   = blockIdx.z;   // 0..3  (split-K)
  const int wm   = w & 1;
  const int wn   = w >> 1;

  const u16* gA[2];
  const u16* gB[2];
  u16* lA[2];
  u16* lB[2];
  #pragma unroll
  for (int i = 0; i < 2; ++i) {
    const int c  = w * 2 + i;            // chunk 0..7 (lane-invariant)
    const int rA = c * 16 + (lane >> 2); // tile row this lane sources
    // swizzled source col-block: j=(lane&3) at LDS holds block j^((row>>1)&3)
    const int kk = (((lane & 3) ^ ((lane >> 3) & 3)) * 8);
    int R = bm * 128 + rA;
    if (R > NROWS) R = NROWS;            // pad rows re-load coef row; never stored
    gA[i] = ((R == NROWS) ? coef : (xb + (size_t)R * D_FF)) + kk;
    gB[i] = wb + (size_t)(bn * 128 + rA) * D_FF + kk;
    lA[i] = &As[c * 512];                // chunk base: wave-uniform
    lB[i] = &Bs[c * 512];
  }

  f32x4 acc[4][4] = {};
  const int r16  = lane & 15;
  const int kswz = (((lane >> 4) ^ ((r16 >> 1) & 3)) * 8);  // swizzled read col

  const int kbeg = kz * (D_FF / 4);
  const int kend = kbeg + (D_FF / 4);    // 2752 = 86 K-steps
  for (int k0 = kbeg; k0 < kend; k0 += 32) {
    #pragma unroll
    for (int i = 0; i < 2; ++i) {
      gload_lds16(gA[i] + k0, lA[i]);
      gload_lds16(gB[i] + k0, lB[i]);
    }
    __syncthreads();               // drains vmcnt: tile resident in LDS
    bf16x8 af[4], bf[4];
    #pragma unroll
    for (int mi = 0; mi < 4; ++mi)
      af[mi] = *(const bf16x8*)&As[(wm * 64 + mi * 16 + r16) * 32 + kswz];
    #pragma unroll
    for (int ni = 0; ni < 4; ++ni)
      bf[ni] = *(const bf16x8*)&Bs[(wn * 64 + ni * 16 + r16) * 32 + kswz];
    #pragma unroll
    for (int mi = 0; mi < 4; ++mi)
      #pragma unroll
      for (int ni = 0; ni < 4; ++ni)
        acc[mi][ni] = __builtin_amdgcn_mfma_f32_16x16x32_bf16(af[mi], bf[ni],
                                                              acc[mi][ni], 0, 0, 0);
    __syncthreads();               // all ds_reads done before next overwrite
  }

  // C/D layout (m89-verified): col = lane&15, row = (lane>>4)*4 + reg
  #pragma unroll
  for (int mi = 0; mi < 4; ++mi) {
    const int rbase = bm * 128 + wm * 64 + mi * 16 + (lane >> 4) * 4;
    #pragma unroll
    for (int ni = 0; ni < 4; ++ni) {
      const int c = bn * 128 + wn * 64 + ni * 16 + r16;
      #pragma unroll
      for (int q = 0; q < 4; ++q) {
        const int r = rbase + q;
        if (r <= NROWS)
          unsafeAtomicAdd(&out[(size_t)r * NDIM + c], acc[mi][ni][q]);
      }
    }
  }
}

// ---------------------------------------------------------------------------
// Fallback GEMM (small workspace): f32 inputs, convert during register staging.
// ---------------------------------------------------------------------------
__global__ __launch_bounds__(256) void gemm_bt_cvt(const float* __restrict__ xv,
                                                   const float* __restrict__ wv,
                                                   const float* __restrict__ cv,
                                                   float* __restrict__ out) {
  __shared__ alignas(16) u16 As[128 * 32];
  __shared__ alignas(16) u16 Bs[128 * 32];
  const int tid  = threadIdx.x;
  const int lane = tid & 63;
  const int bn   = blockIdx.x;
  const int bm   = blockIdx.y;
  const int wid  = tid >> 6;
  const int wm   = wid & 1;
  const int wn   = wid >> 1;

  const int r0 = tid >> 2;
  const int kk = (tid & 3) * 8;

  const float* ag[2];
  const float* bg[2];
  u16* al[2];
  u16* bl[2];
  #pragma unroll
  for (int p = 0; p < 2; ++p) {
    const int rl = p * 64 + r0;
    int R = bm * 128 + rl;
    if (R > NROWS) R = NROWS;
    ag[p] = ((R == NROWS) ? cv : (xv + (size_t)R * D_FF)) + kk;
    bg[p] = wv + (size_t)(bn * 128 + rl) * D_FF + kk;
    al[p] = &As[rl * 32 + kk];
    bl[p] = &Bs[rl * 32 + kk];
  }

  f32x4 acc[4][4] = {};
  const int r16 = lane & 15;
  const int kg  = (lane >> 4) * 8;

  for (int k0 = 0; k0 < D_FF; k0 += 32) {
    u16x8 sa[2], sb[2];
    #pragma unroll
    for (int p = 0; p < 2; ++p) {
      const float* pa = ag[p] + k0;
      const float* pb = bg[p] + k0;
      sa[p] = pack8(*(const float4*)pa, *(const float4*)(pa + 4));
      sb[p] = pack8(*(const float4*)pb, *(const float4*)(pb + 4));
    }
    __syncthreads();
    #pragma unroll
    for (int p = 0; p < 2; ++p) {
      *(u16x8*)al[p] = sa[p];
      *(u16x8*)bl[p] = sb[p];
    }
    __syncthreads();
    bf16x8 af[4], bf[4];
    #pragma unroll
    for (int mi = 0; mi < 4; ++mi)
      af[mi] = *(const bf16x8*)&As[(wm * 64 + mi * 16 + r16) * 32 + kg];
    #pragma unroll
    for (int ni = 0; ni < 4; ++ni)
      bf[ni] = *(const bf16x8*)&Bs[(wn * 64 + ni * 16 + r16) * 32 + kg];
    #pragma unroll
    for (int mi = 0; mi < 4; ++mi)
      #pragma unroll
      for (int ni = 0; ni < 4; ++ni)
        acc[mi][ni] = __builtin_amdgcn_mfma_f32_16x16x32_bf16(af[mi], bf[ni],
                                                              acc[mi][ni], 0, 0, 0);
  }

  #pragma unroll
  for (int mi = 0; mi < 4; ++mi) {
    const int rbase = bm * 128 + wm * 64 + mi * 16 + (lane >> 4) * 4;
    #pragma unroll
    for (int ni = 0; ni < 4; ++ni) {
      const int c = bn * 128 + wn * 64 + ni * 16 + r16;
      #pragma unroll
      for (int q = 0; q < 4; ++q) {
        const int r = rbase + q;
        if (r <= NROWS)
          out[(size_t)r * NDIM + c] = acc[mi][ni][q];
      }
    }
  }
}

extern "C" void kernel_launch(void* const* d_in, const int* in_sizes, int n_in,
                              void* d_out, int out_size, void* d_ws, size_t ws_size,
                              hipStream_t stream) {
  (void)in_sizes; (void)n_in; (void)out_size;
  const float* x    = (const float*)d_in[0];   // f32 (1,2048,11008)
  const float* w    = (const float*)d_in[1];   // f32 (4096,11008)
  const float* xdec = (const float*)d_in[2];   // f32 (4403)
  const int*   mn   = (const int*)d_in[3];     // int32 (11008)
  float* out = (float*)d_out;                  // f32 (2049*4096)

  char* ws = (char*)d_ws;
  int*   counts = (int*)ws;                        // 44032 B
  float* coef_f = (float*)(ws + 44032);            // 44032 B
  u16*   coef_h = (u16*)(ws + 88064);              // 22016 B
  u16*   xb     = (u16*)(ws + 110080);             // 45,088,768 B
  u16*   wb     = (u16*)(ws + 110080 + 45088768ull); // 90,177,536 B
  const size_t need_fast = 110080ull + 45088768ull + 90177536ull;
  const bool fast = (ws_size >= need_fast);
  // rowmask (2048*172*8 = 2,818,048 B): dead after count_bits. In the fast
  // path alias it into wb (cvt of W runs after count_bits, stream-ordered);
  // in the slow path use the xb region.
  u64* rowmask = (u64*)(fast ? (void*)wb : (void*)xb);

  hipMemsetAsync(d_ws, 0, 110080, stream);         // coef_f/coef_h zeroed
  row_topk_mask<<<NROWS, 256, 0, stream>>>(x, rowmask, fast ? xb : (u16*)0);
  count_bits<<<NWORD, 256, 0, stream>>>(rowmask, counts);
  build_coef<<<1, 256, 0, stream>>>(counts, mn, xdec, coef_f, coef_h);

  if (fast) {
    cvt_bf16<<<(NDIM * D_FF / 8 + 255) / 256, 256, 0, stream>>>(w, wb, NDIM * D_FF / 8);
    hipMemsetAsync(out, 0, (size_t)(NROWS + 1) * NDIM * sizeof(float), stream);
    gemm_lds<<<dim3(32, 17, 4), 256, 0, stream>>>(xb, wb, coef_h, out);
  } else {
    gemm_bt_cvt<<<dim3(32, 17), 256, 0, stream>>>(x, w, coef_f, out);
  }
}